// Round 4
// baseline (909.514 us; speedup 1.0000x reference)
//
#include <hip/hip_runtime.h>
#include <stdint.h>

// VQ-VAE codebook argmin, f32 in / f32 out.
// R9: Z-stationary round. R5-R8 post-mortem: k_argmin was bound by Z RE-FETCH
// (1.1GB HBM = Z re-staged per tile, thrashing L2; 900cyc drains at each
// barrier). R8's launch_bounds(256,4) additionally forced VGPR=64 -> 274MB of
// scratch spill (WRITE_SIZE). Fix: stage each block's Z (64 rows x K=512 bf16
// = 64KB) into LDS ONCE; stream only W (8KB/kstep) with the R5-proven
// syncthreads pair (no manual pipeline - R6 lesson). LDS 72KB -> 2 blocks/CU
// for inter-block latency hiding. No launch-bounds min (R8 lesson); 256-thr
// blocks need only <=256 VGPR for 2 blocks/CU. SUPERS=4 with super=b&3,
// XCD=b&7 kept from R8: one 2MB W-slice per XCD, L2-resident.
// Ranking: 16 tiles x top-2/(row,slice) -> top-4/super x 4 supers (R8-proven
// candidate set); k_exact numerics unchanged (16 candidates, R4-proven).

#define B_ROWS 32768
#define DIM    512
#define KCODES 8192
#define SUPERS 4
#define TILES  16   // per super: 16 tiles * 128 = 2048 codes
#define ZROWS  64   // Z rows per block (stationary in LDS, full K)

typedef short bhalf8_t __attribute__((ext_vector_type(8)));
typedef float f32x4_t  __attribute__((ext_vector_type(4)));

__device__ __forceinline__ float b2f(unsigned short u) {
    return __uint_as_float(((unsigned int)u) << 16);
}
__device__ __forceinline__ unsigned short f2b(float f) {  // RNE
    unsigned int x = __float_as_uint(f);
    return (unsigned short)((x + 0x7FFFu + ((x >> 16) & 1u)) >> 16);
}
__device__ __forceinline__ void gl_lds16(const void* g, void* l) {
    __builtin_amdgcn_global_load_lds(
        (const __attribute__((address_space(1))) unsigned int*)g,
        (__attribute__((address_space(3))) unsigned int*)l, 16, 0, 0);
}

// ---------- K0: f32 -> bf16 (hi only) ----------
__global__ __launch_bounds__(256) void k_split(const float4* __restrict__ src,
                                               ushort4* __restrict__ dst, int n4) {
    int i = blockIdx.x * 256 + threadIdx.x;
    int stride = gridDim.x * 256;
    for (; i < n4; i += stride) {
        float4 v = src[i];
        ushort4 h;
        h.x = f2b(v.x); h.y = f2b(v.y); h.z = f2b(v.z); h.w = f2b(v.w);
        dst[i] = h;
    }
}

// ---------- K1: numpy-pairwise-emulated row sum of squares (R4-proven) ----------
__global__ __launch_bounds__(256) void k_pairsq(const float* __restrict__ X,
                                                float* __restrict__ out, int nrows) {
    int wid = threadIdx.x >> 6, lane = threadIdx.x & 63;
    int r = blockIdx.x * 4 + wid;
    if (r >= nrows) return;
    int b = lane >> 3, j = lane & 7;
    float acc = 0.f;
    if (b < 4) {
        const float* x = X + (size_t)r * DIM + b * 128 + j;
        float v = x[0];
        acc = __fmul_rn(v, v);
        for (int i = 1; i < 16; i++) {
            float w = x[8 * i];
            acc = __fadd_rn(acc, __fmul_rn(w, w));
        }
    }
    float t = __fadd_rn(acc, __shfl_xor(acc, 1));
    t = __fadd_rn(t, __shfl_xor(t, 2));
    t = __fadd_rn(t, __shfl_xor(t, 4));
    float u = __fadd_rn(t, __shfl_xor(t, 8));
    u = __fadd_rn(u, __shfl_xor(u, 16));
    if (lane == 0) out[r] = u;
}

// ---------- K2: Z-stationary bf16 MFMA GEMM + packed top-2 -> top-4/super ----------
// LDS map (72KB): [0,64K) = Z, 64 rows x 512 k, 16 fragment-major 32-k slices
//                 [64K,72K) = W slice, 128 codes x 32 k, fragment-major
// Fragment-major 32-k slice (HW-verified R6-R8): element (row, kseg) at byte
//   (row>>4)*1024 + kseg*256 + (row&15)*16
// Wave-tile 32x64: wm in {0,1} over 64 Z rows, wn in {0,1} over 128 codes.
// A-frag read: zbase + ks*4096 + (wm*2+f)*1024 + lane*16  (contiguous 1024B,
// conflict-free). global_load_lds dest stays LINEAR; the layout permutation
// is applied to the per-lane GLOBAL source address (both-sides-or-neither).
__global__ __launch_bounds__(256) void k_argmin(const unsigned short* __restrict__ Zh,
                                                const unsigned short* __restrict__ Wh,
                                                const float* __restrict__ ww,
                                                float2* __restrict__ part) {
    __shared__ alignas(16) unsigned char smem[73728];
    const int tid = threadIdx.x;
    const int lane = tid & 63, w = tid >> 6;
    const int wm = w >> 1, wn = w & 1;
    const int lane15 = lane & 15, q = lane >> 4;
    const int b = blockIdx.x;
    const int super = b & 3;          // XCD = b&7 -> one 2MB W-slice per XCD (L2-resident)
    const int rb = (b >> 2) * ZROWS;

    unsigned char* zl = smem;                  // 64KB Z
    unsigned char* wl = smem + 65536;          // 8KB W slice

    // ---- Z prologue: stage 64 rows x 512 k once (16 gl_lds16 per thread) ----
    // slot s = i*256 + tid; byte dest = s*16 (linear; per-wave base + lane*16).
    // decode: ks = s>>8, g = (s>>6)&3, kseg = (s>>4)&3, m = s&15;
    //         row = g*16+m, k = ks*32 + kseg*8.
    {
        const int m = tid & 15;
        const int kseg8 = ((tid >> 4) & 3) << 3;
#pragma unroll
        for (int i = 0; i < 16; i++) {
            const int s = i * 256 + tid;
            const int ks = s >> 8;
            const int g = (s >> 6) & 3;
            gl_lds16(Zh + (size_t)(rb + g * 16 + m) * DIM + ks * 32 + kseg8,
                     zl + s * 16);
        }
    }

    // W staging decode (R5-proven mapping): thread tid fills slots tid
    // (codes 0..63) and tid+256 (codes 64..127, dst+4096).
    const int rowO0 = ((tid >> 6) << 4) | (tid & 15);
    const int kO0   = ((tid >> 4) & 3) << 3;
    const int dst0  = tid * 16;

    uint32_t p1[2][4], p2[2][4];
#pragma unroll
    for (int i = 0; i < 2; i++)
#pragma unroll
        for (int jj = 0; jj < 4; jj++) { p1[i][jj] = 0xFFFFFFFFu; p2[i][jj] = 0xFFFFFFFFu; }

    __syncthreads();   // Z staged (compiler drains vmcnt before barrier)

    for (int tl = 0; tl < TILES; ++tl) {
        const int nt = super * 2048 + tl * 128;
        f32x4_t acc[2][4];
#pragma unroll
        for (int i = 0; i < 2; i++)
#pragma unroll
            for (int jj = 0; jj < 4; jj++) acc[i][jj] = (f32x4_t){0.f, 0.f, 0.f, 0.f};

        for (int ks = 0; ks < 16; ++ks) {
            __syncthreads();  // prior W readers done (also orders vs Z prologue on tl=0)
            const int kg = ks * 32 + kO0;
            gl_lds16(Wh + (size_t)(nt + rowO0) * DIM + kg,      wl + dst0);
            gl_lds16(Wh + (size_t)(nt + rowO0 + 64) * DIM + kg, wl + 4096 + dst0);
            __syncthreads();  // W staged (compiler-managed vmcnt drain)

            bhalf8_t af[2], bf[4];
#pragma unroll
            for (int f = 0; f < 2; f++)
                af[f] = *(const bhalf8_t*)(zl + ks * 4096 + (wm * 2 + f) * 1024 + lane * 16);
#pragma unroll
            for (int f = 0; f < 4; f++)
                bf[f] = *(const bhalf8_t*)(wl + (wn * 4096 + f * 1024) + lane * 16);
#pragma unroll
            for (int fm = 0; fm < 2; fm++)
#pragma unroll
                for (int fn = 0; fn < 4; fn++)
                    acc[fm][fn] = __builtin_amdgcn_mfma_f32_16x16x32_bf16(af[fm], bf[fn], acc[fm][fn], 0, 0, 0);
        }

        // epilogue: s' = (ww[n]+0.5) - 2*dot (positive => float bits monotonic);
        // pack: high-25 bits | 7-bit id (tl*4+fn, <64). Strict '<' ascending
        // (tl,fn) insert => smaller n wins ties within a slice.
        float cb[4];
#pragma unroll
        for (int fn = 0; fn < 4; fn++)
            cb[fn] = ww[nt + wn * 64 + fn * 16 + lane15] + 0.5f;
#pragma unroll
        for (int fm = 0; fm < 2; fm++)
#pragma unroll
            for (int r = 0; r < 4; r++)
#pragma unroll
                for (int fn = 0; fn < 4; fn++) {
                    float sv = fmaf(-2.0f, acc[fm][fn][r], cb[fn]);
                    uint32_t pk = (__float_as_uint(sv) & 0xFFFFFF80u) | (uint32_t)(tl * 4 + fn);
                    if (pk < p1[fm][r]) { p2[fm][r] = p1[fm][r]; p1[fm][r] = pk; }
                    else if (pk < p2[fm][r]) { p2[fm][r] = pk; }
                }
    }

    // per-row top-4 of 64 packed keys via LDS (reuses Z region)
    __syncthreads();
    uint32_t* keys = (uint32_t*)smem;   // [64 rows][32 slices][2 slots] = 16KB
#pragma unroll
    for (int fm = 0; fm < 2; fm++)
#pragma unroll
        for (int r = 0; r < 4; r++) {
            int row = wm * 32 + fm * 16 + q * 4 + r;   // C/D row = (lane>>4)*4 + reg
            int slice = wn * 16 + lane15;
            keys[(row * 32 + slice) * 2 + 0] = p1[fm][r];
            keys[(row * 32 + slice) * 2 + 1] = p2[fm][r];
        }
    __syncthreads();
    if (tid < ZROWS) {
        int row = tid;
        int rglob = rb + row;
        for (int s = 0; s < 4; s++) {
            uint32_t bk = 0xFFFFFFFFu; int be = 0;
            for (int e = 0; e < 64; e++) {
                uint32_t k = keys[row * 64 + e];
                if (k < bk) { bk = k; be = e; }
            }
            int slice = be >> 1;
            int id = (int)(bk & 127u);
            int n = super * 2048 + (id >> 2) * 128 + (slice >> 4) * 64 + (id & 3) * 16 + (slice & 15);
            part[((size_t)rglob * SUPERS + super) * 4 + s] =
                make_float2(__uint_as_float(bk), __int_as_float(n));
            keys[row * 64 + be] = 0xFFFFFFFFu;  // consume
        }
    }
}

// ---------- K3: exact numpy-f32 re-rank of 16 candidates, outputs (R4-proven) ----------
__global__ __launch_bounds__(256) void k_exact(const float* __restrict__ Zf,
                                               const float* __restrict__ Wf,
                                               const float2* __restrict__ part,
                                               const float* __restrict__ zz,
                                               const float* __restrict__ ww,
                                               float* __restrict__ outf,
                                               float* __restrict__ lossp) {
    __shared__ float wsum[4];
    int wid = threadIdx.x >> 6, lane = threadIdx.x & 63;
    int r = blockIdx.x * 4 + wid;
    int c = lane >> 2, j = lane & 3;   // candidate 0..15, SSE lane 0..3

    // candidates: 4 supers x top-4
    float2 P = part[((size_t)r * SUPERS + (c >> 2)) * 4 + (c & 3)];
    int n = __float_as_int(P.y);
    n = min(max(n, 0), KCODES - 1);

    // numpy einsum baseline-SIMD: 4 stride-4 f32 accumulators (mul+add, no FMA)
    const float* zp = Zf + (size_t)r * DIM + j;
    const float* wp = Wf + (size_t)n * DIM + j;
    float acc = 0.f;
    for (int i = 0; i < 128; i++)
        acc = __fadd_rn(acc, __fmul_rn(zp[4 * i], wp[4 * i]));
    float t = __fadd_rn(acc, __shfl_xor(acc, 1));
    t = __fadd_rn(t, __shfl_xor(t, 2));
    float dot = __shfl(t, c * 4);

    float t1 = __fadd_rn(zz[r], ww[n]);
    float t2 = __fmul_rn(2.0f, dot);
    float d2 = __fadd_rn(t1, -t2);

    float bd = (j == 0) ? d2 : 3.4e38f;
    int   bn = (j == 0) ? n  : 0x7FFFFFFF;
#pragma unroll
    for (int off = 32; off; off >>= 1) {
        float od = __shfl_xor(bd, off);
        int   on = __shfl_xor(bn, off);
        if (od < bd || (od == bd && on < bn)) { bd = od; bn = on; }
    }
    int idx = bn;

    float4 wa = *(const float4*)(Wf + (size_t)idx * DIM + lane * 8);
    float4 wb = *(const float4*)(Wf + (size_t)idx * DIM + lane * 8 + 4);
    float4 za = *(const float4*)(Zf + (size_t)r   * DIM + lane * 8);
    float4 zb = *(const float4*)(Zf + (size_t)r   * DIM + lane * 8 + 4);
    *(float4*)(outf + (size_t)r * DIM + lane * 8)     = wa;
    *(float4*)(outf + (size_t)r * DIM + lane * 8 + 4) = wb;
    float d0 = za.x - wa.x, d1 = za.y - wa.y, dd2 = za.z - wa.z, d3 = za.w - wa.w;
    float d4 = zb.x - wb.x, d5 = zb.y - wb.y, d6 = zb.z - wb.z, d7 = zb.w - wb.w;
    float ls = d0*d0 + d1*d1 + dd2*dd2 + d3*d3 + d4*d4 + d5*d5 + d6*d6 + d7*d7;
#pragma unroll
    for (int off = 32; off; off >>= 1) ls += __shfl_xor(ls, off);
    if (lane == 0) {
        outf[(size_t)B_ROWS * DIM + r] = (float)idx;
        wsum[wid] = ls;
    }
    __syncthreads();
    if (threadIdx.x == 0) lossp[blockIdx.x] = wsum[0] + wsum[1] + wsum[2] + wsum[3];
}

// ---------- K4: loss reduction ----------
__global__ __launch_bounds__(256) void k_loss(const float* __restrict__ lossp,
                                              float* __restrict__ outf) {
    __shared__ float sm[256];
    float a = 0.f;
    for (int i = threadIdx.x; i < 8192; i += 256) a += lossp[i];
    sm[threadIdx.x] = a;
    __syncthreads();
    for (int s = 128; s; s >>= 1) {
        if (threadIdx.x < s) sm[threadIdx.x] += sm[threadIdx.x + s];
        __syncthreads();
    }
    if (threadIdx.x == 0)
        outf[(size_t)B_ROWS * DIM + B_ROWS] = 1.25f * sm[0] / 16777216.0f;
}

extern "C" void kernel_launch(void* const* d_in, const int* in_sizes, int n_in,
                              void* d_out, int out_size, void* d_ws, size_t ws_size,
                              hipStream_t stream) {
    (void)in_sizes; (void)n_in; (void)out_size; (void)ws_size;
    const float* Zf = (const float*)d_in[0];   // [32768, 512] f32
    const float* Wf = (const float*)d_in[1];   // [8192, 512]  f32
    float* outf = (float*)d_out;               // f32: z_q | indices | loss

    // bf16 scratch inside d_out's z_q region (64 MB): Zh 32MB @0 | Wh 8MB @32MB.
    // k_exact overwrites it with the final z_q (k_argmin has completed by then).
    unsigned short* Zh = (unsigned short*)d_out;
    unsigned short* Wh = (unsigned short*)((char*)d_out + (32ull << 20));

    // ws (4.39 MB, proven): ww 32KB @0 | zz 128KB @32K | lossp 32KB @160K | part 4MB @192K
    // part layout: [row][super(4)][4 entries] float2 = 4MB.
    float*  ww    = (float*)d_ws;
    float*  zz    = (float*)((char*)d_ws + 32768);
    float*  lossp = (float*)((char*)d_ws + 163840);
    float2* partp = (float2*)((char*)d_ws + 196608);

    k_split<<<1024, 256, 0, stream>>>((const float4*)Zf, (ushort4*)Zh, B_ROWS * DIM / 4);
    k_split<<<512,  256, 0, stream>>>((const float4*)Wf, (ushort4*)Wh, KCODES * DIM / 4);
    k_pairsq<<<KCODES / 4, 256, 0, stream>>>(Wf, ww, KCODES);
    k_pairsq<<<B_ROWS / 4, 256, 0, stream>>>(Zf, zz, B_ROWS);
    k_argmin<<<(B_ROWS / ZROWS) * SUPERS, 256, 0, stream>>>(Zh, Wh, ww, partp);
    k_exact<<<B_ROWS / 4, 256, 0, stream>>>(Zf, Wf, partp, zz, ww, outf, lossp);
    k_loss<<<1, 256, 0, stream>>>(lossp, outf);
}

// Round 5
// 844.856 us; speedup vs baseline: 1.0765x; 1.0765x over previous
//
#include <hip/hip_runtime.h>
#include <stdint.h>

// VQ-VAE codebook argmin, f32 in / f32 out.
// R10: pipeline round. R9 proved traffic is fixed (FETCH 100MB = compulsory,
// HBM 2% of peak) but time didn't move: the serial
// {barrier; stage W; barrier(vmcnt0-drain); compute} exposes full L2 latency
// every one of 512 barrier pairs (~730cyc/step measured). Fix = catalog
// minimum-2-phase: double-buffer the 8KB W slice (LDS 72->80KB, still exactly
// 2 blocks/CU), per step {STAGE W(t+1)->buf^1; compute buf; __syncthreads()}.
// Loads are issued a full compute-phase before the drain -> latency hidden;
// one barrier/step instead of two. Even/odd unroll keeps buffer pointers
// static (no scratch). R6's failure mode doesn't apply: loads are 2x16B
// L2-resident (not 16KB HBM), occupancy healthy (VGPR 88), compiler-managed
// waits only. Also: ww loads hoisted to tile start; final-reduce keys stride
// padded 64->65 (was a 32-way-conflict serial scan = the constant 7.9e6
// SQ_LDS_BANK_CONFLICT across R5-R9).
// Ranking: 16 tiles x top-2/(row,slice) -> top-4/super x 4 supers (R8/R9-
// proven candidate set); k_exact numerics unchanged (16 cands, R4-proven).

#define B_ROWS 32768
#define DIM    512
#define KCODES 8192
#define SUPERS 4
#define TILES  16   // per super: 16 tiles * 128 = 2048 codes
#define ZROWS  64   // Z rows per block (stationary in LDS, full K)

typedef short bhalf8_t __attribute__((ext_vector_type(8)));
typedef float f32x4_t  __attribute__((ext_vector_type(4)));

__device__ __forceinline__ float b2f(unsigned short u) {
    return __uint_as_float(((unsigned int)u) << 16);
}
__device__ __forceinline__ unsigned short f2b(float f) {  // RNE
    unsigned int x = __float_as_uint(f);
    return (unsigned short)((x + 0x7FFFu + ((x >> 16) & 1u)) >> 16);
}
__device__ __forceinline__ void gl_lds16(const void* g, void* l) {
    __builtin_amdgcn_global_load_lds(
        (const __attribute__((address_space(1))) unsigned int*)g,
        (__attribute__((address_space(3))) unsigned int*)l, 16, 0, 0);
}

// ---------- K0: f32 -> bf16 (hi only) ----------
__global__ __launch_bounds__(256) void k_split(const float4* __restrict__ src,
                                               ushort4* __restrict__ dst, int n4) {
    int i = blockIdx.x * 256 + threadIdx.x;
    int stride = gridDim.x * 256;
    for (; i < n4; i += stride) {
        float4 v = src[i];
        ushort4 h;
        h.x = f2b(v.x); h.y = f2b(v.y); h.z = f2b(v.z); h.w = f2b(v.w);
        dst[i] = h;
    }
}

// ---------- K1: numpy-pairwise-emulated row sum of squares (R4-proven) ----------
__global__ __launch_bounds__(256) void k_pairsq(const float* __restrict__ X,
                                                float* __restrict__ out, int nrows) {
    int wid = threadIdx.x >> 6, lane = threadIdx.x & 63;
    int r = blockIdx.x * 4 + wid;
    if (r >= nrows) return;
    int b = lane >> 3, j = lane & 7;
    float acc = 0.f;
    if (b < 4) {
        const float* x = X + (size_t)r * DIM + b * 128 + j;
        float v = x[0];
        acc = __fmul_rn(v, v);
        for (int i = 1; i < 16; i++) {
            float w = x[8 * i];
            acc = __fadd_rn(acc, __fmul_rn(w, w));
        }
    }
    float t = __fadd_rn(acc, __shfl_xor(acc, 1));
    t = __fadd_rn(t, __shfl_xor(t, 2));
    t = __fadd_rn(t, __shfl_xor(t, 4));
    float u = __fadd_rn(t, __shfl_xor(t, 8));
    u = __fadd_rn(u, __shfl_xor(u, 16));
    if (lane == 0) out[r] = u;
}

// ---------- K2: Z-stationary bf16 MFMA GEMM, W double-buffered ----------
// LDS map (80KB): [0,64K) Z (16 fragment-major 32-k slices)
//                 [64K,72K) W buf0 | [72K,80K) W buf1
// Fragment-major 32-k slice (HW-verified R6-R9): element (row, kseg) at byte
//   (row>>4)*1024 + kseg*256 + (row&15)*16
// Wave-tile 32x64: wm in {0,1} over 64 Z rows, wn in {0,1} over 128 codes.
// Conflict-free wave reads: base + f*1024 + lane*16 (contiguous 1024B).
// global_load_lds dest stays LINEAR; layout permutation applied to per-lane
// GLOBAL source address (both-sides-or-neither rule).
__device__ __forceinline__ void compute_slice2(const unsigned char* zl, int ks,
                                               const unsigned char* wbuf,
                                               int wm, int wn, int lane,
                                               f32x4_t acc[2][4]) {
    bhalf8_t af[2], bf[4];
#pragma unroll
    for (int f = 0; f < 2; f++)
        af[f] = *(const bhalf8_t*)(zl + ks * 4096 + (wm * 2 + f) * 1024 + lane * 16);
#pragma unroll
    for (int f = 0; f < 4; f++)
        bf[f] = *(const bhalf8_t*)(wbuf + wn * 4096 + f * 1024 + lane * 16);
#pragma unroll
    for (int fm = 0; fm < 2; fm++)
#pragma unroll
        for (int fn = 0; fn < 4; fn++)
            acc[fm][fn] = __builtin_amdgcn_mfma_f32_16x16x32_bf16(af[fm], bf[fn], acc[fm][fn], 0, 0, 0);
}

__global__ __launch_bounds__(256) void k_argmin(const unsigned short* __restrict__ Zh,
                                                const unsigned short* __restrict__ Wh,
                                                const float* __restrict__ ww,
                                                float2* __restrict__ part) {
    __shared__ alignas(16) unsigned char smem[81920];
    const int tid = threadIdx.x;
    const int lane = tid & 63, w = tid >> 6;
    const int wm = w >> 1, wn = w & 1;
    const int lane15 = lane & 15, q = lane >> 4;
    const int b = blockIdx.x;
    const int super = b & 3;          // XCD = b&7 -> one 2MB W-slice per XCD (L2-resident)
    const int rb = (b >> 2) * ZROWS;

    unsigned char* zl  = smem;                    // 64KB Z
    unsigned char* wl0 = smem + 65536;            // 8KB W buf0
    unsigned char* wl1 = smem + 65536 + 8192;     // 8KB W buf1

    // ---- Z prologue: stage 64 rows x 512 k once (16 gl_lds16 per thread) ----
    // slot s = i*256 + tid; dest byte = s*16 (linear, lane-contiguous).
    // decode: ks=s>>8, g=(s>>6)&3, kseg=(s>>4)&3, m=s&15; row=g*16+m.
    {
        const int m = tid & 15;
        const int kseg8 = ((tid >> 4) & 3) << 3;
#pragma unroll
        for (int i = 0; i < 16; i++) {
            const int s = i * 256 + tid;
            const int ks = s >> 8;
            const int g = (s >> 6) & 3;
            gl_lds16(Zh + (size_t)(rb + g * 16 + m) * DIM + ks * 32 + kseg8,
                     zl + s * 16);
        }
    }

    // W staging decode (R5-proven): thread tid fills slot tid (codes 0..63)
    // and slot tid+256 (codes 64..127, dst+4096) of the 8KB slice.
    const int rowO0 = ((tid >> 6) << 4) | (tid & 15);
    const int kO0   = ((tid >> 4) & 3) << 3;
    const int dst0  = tid * 16;

#define STAGE_W(ST, WB)                                                          \
    do {                                                                         \
        const int _tl = (ST) >> 4;                                               \
        const int _nt = super * 2048 + _tl * 128;                                \
        const int _kg = ((ST) & 15) * 32 + kO0;                                  \
        gl_lds16(Wh + (size_t)(_nt + rowO0) * DIM + _kg,      (WB) + dst0);      \
        gl_lds16(Wh + (size_t)(_nt + rowO0 + 64) * DIM + _kg, (WB) + 4096 + dst0);\
    } while (0)

    uint32_t p1[2][4], p2[2][4];
#pragma unroll
    for (int i = 0; i < 2; i++)
#pragma unroll
        for (int jj = 0; jj < 4; jj++) { p1[i][jj] = 0xFFFFFFFFu; p2[i][jj] = 0xFFFFFFFFu; }

    STAGE_W(0, wl0);
    __syncthreads();   // Z + W step-0 staged (compiler drains vmcnt before barrier)

    for (int tl = 0; tl < TILES; ++tl) {
        const int nt = super * 2048 + tl * 128;

        // hoisted epilogue operands: in flight during step 0 of this tile
        float cb[4];
#pragma unroll
        for (int fn = 0; fn < 4; fn++)
            cb[fn] = ww[nt + wn * 64 + fn * 16 + lane15] + 0.5f;

        f32x4_t acc[2][4];
#pragma unroll
        for (int i = 0; i < 2; i++)
#pragma unroll
            for (int jj = 0; jj < 4; jj++) acc[i][jj] = (f32x4_t){0.f, 0.f, 0.f, 0.f};

        for (int k2 = 0; k2 < 16; k2 += 2) {
            const int st = tl * 16 + k2;
            // even step: stage st+1 -> buf1, compute buf0 (ks = k2)
            STAGE_W(st + 1, wl1);
            compute_slice2(zl, k2, wl0, wm, wn, lane, acc);
            __syncthreads();   // drains st+1 loads (issued a compute-phase ago)
            // odd step: stage st+2 -> buf0 (if any), compute buf1 (ks = k2+1)
            if (st + 2 < SUPERS * 0 + TILES * 16) {  // st+2 < 256 (uniform)
                STAGE_W(st + 2, wl0);
            }
            compute_slice2(zl, k2 + 1, wl1, wm, wn, lane, acc);
            __syncthreads();
        }

        // epilogue: s' = (ww[n]+0.5) - 2*dot (positive => float bits monotonic);
        // pack: high-25 bits | 7-bit id (tl*4+fn, <64). Strict '<' ascending
        // (tl,fn) insert => smaller n wins ties within a slice.
#pragma unroll
        for (int fm = 0; fm < 2; fm++)
#pragma unroll
            for (int r = 0; r < 4; r++)
#pragma unroll
                for (int fn = 0; fn < 4; fn++) {
                    float sv = fmaf(-2.0f, acc[fm][fn][r], cb[fn]);
                    uint32_t pk = (__float_as_uint(sv) & 0xFFFFFF80u) | (uint32_t)(tl * 4 + fn);
                    if (pk < p1[fm][r]) { p2[fm][r] = p1[fm][r]; p1[fm][r] = pk; }
                    else if (pk < p2[fm][r]) { p2[fm][r] = pk; }
                }
    }
#undef STAGE_W

    // per-row top-4 of 64 packed keys via LDS (reuses Z region; stride 65
    // breaks the 32-way conflict of the serial scan: bank = (row+2*slice)%32)
    __syncthreads();
    uint32_t* keys = (uint32_t*)smem;   // [64 rows][stride 65]
#pragma unroll
    for (int fm = 0; fm < 2; fm++)
#pragma unroll
        for (int r = 0; r < 4; r++) {
            int row = wm * 32 + fm * 16 + q * 4 + r;   // C/D row = (lane>>4)*4 + reg
            int slice = wn * 16 + lane15;
            keys[row * 65 + slice * 2 + 0] = p1[fm][r];
            keys[row * 65 + slice * 2 + 1] = p2[fm][r];
        }
    __syncthreads();
    if (tid < ZROWS) {
        int row = tid;
        int rglob = rb + row;
        for (int s = 0; s < 4; s++) {
            uint32_t bk = 0xFFFFFFFFu; int be = 0;
            for (int e = 0; e < 64; e++) {
                uint32_t k = keys[row * 65 + e];
                if (k < bk) { bk = k; be = e; }
            }
            int slice = be >> 1;
            int id = (int)(bk & 127u);
            int n = super * 2048 + (id >> 2) * 128 + (slice >> 4) * 64 + (id & 3) * 16 + (slice & 15);
            part[((size_t)rglob * SUPERS + super) * 4 + s] =
                make_float2(__uint_as_float(bk), __int_as_float(n));
            keys[row * 65 + be] = 0xFFFFFFFFu;  // consume
        }
    }
}

// ---------- K3: exact numpy-f32 re-rank of 16 candidates, outputs (R4-proven) ----------
__global__ __launch_bounds__(256) void k_exact(const float* __restrict__ Zf,
                                               const float* __restrict__ Wf,
                                               const float2* __restrict__ part,
                                               const float* __restrict__ zz,
                                               const float* __restrict__ ww,
                                               float* __restrict__ outf,
                                               float* __restrict__ lossp) {
    __shared__ float wsum[4];
    int wid = threadIdx.x >> 6, lane = threadIdx.x & 63;
    int r = blockIdx.x * 4 + wid;
    int c = lane >> 2, j = lane & 3;   // candidate 0..15, SSE lane 0..3

    // candidates: 4 supers x top-4
    float2 P = part[((size_t)r * SUPERS + (c >> 2)) * 4 + (c & 3)];
    int n = __float_as_int(P.y);
    n = min(max(n, 0), KCODES - 1);

    // numpy einsum baseline-SIMD: 4 stride-4 f32 accumulators (mul+add, no FMA)
    const float* zp = Zf + (size_t)r * DIM + j;
    const float* wp = Wf + (size_t)n * DIM + j;
    float acc = 0.f;
    for (int i = 0; i < 128; i++)
        acc = __fadd_rn(acc, __fmul_rn(zp[4 * i], wp[4 * i]));
    float t = __fadd_rn(acc, __shfl_xor(acc, 1));
    t = __fadd_rn(t, __shfl_xor(t, 2));
    float dot = __shfl(t, c * 4);

    float t1 = __fadd_rn(zz[r], ww[n]);
    float t2 = __fmul_rn(2.0f, dot);
    float d2 = __fadd_rn(t1, -t2);

    float bd = (j == 0) ? d2 : 3.4e38f;
    int   bn = (j == 0) ? n  : 0x7FFFFFFF;
#pragma unroll
    for (int off = 32; off; off >>= 1) {
        float od = __shfl_xor(bd, off);
        int   on = __shfl_xor(bn, off);
        if (od < bd || (od == bd && on < bn)) { bd = od; bn = on; }
    }
    int idx = bn;

    float4 wa = *(const float4*)(Wf + (size_t)idx * DIM + lane * 8);
    float4 wb = *(const float4*)(Wf + (size_t)idx * DIM + lane * 8 + 4);
    float4 za = *(const float4*)(Zf + (size_t)r   * DIM + lane * 8);
    float4 zb = *(const float4*)(Zf + (size_t)r   * DIM + lane * 8 + 4);
    *(float4*)(outf + (size_t)r * DIM + lane * 8)     = wa;
    *(float4*)(outf + (size_t)r * DIM + lane * 8 + 4) = wb;
    float d0 = za.x - wa.x, d1 = za.y - wa.y, dd2 = za.z - wa.z, d3 = za.w - wa.w;
    float d4 = zb.x - wb.x, d5 = zb.y - wb.y, d6 = zb.z - wb.z, d7 = zb.w - wb.w;
    float ls = d0*d0 + d1*d1 + dd2*dd2 + d3*d3 + d4*d4 + d5*d5 + d6*d6 + d7*d7;
#pragma unroll
    for (int off = 32; off; off >>= 1) ls += __shfl_xor(ls, off);
    if (lane == 0) {
        outf[(size_t)B_ROWS * DIM + r] = (float)idx;
        wsum[wid] = ls;
    }
    __syncthreads();
    if (threadIdx.x == 0) lossp[blockIdx.x] = wsum[0] + wsum[1] + wsum[2] + wsum[3];
}

// ---------- K4: loss reduction ----------
__global__ __launch_bounds__(256) void k_loss(const float* __restrict__ lossp,
                                              float* __restrict__ outf) {
    __shared__ float sm[256];
    float a = 0.f;
    for (int i = threadIdx.x; i < 8192; i += 256) a += lossp[i];
    sm[threadIdx.x] = a;
    __syncthreads();
    for (int s = 128; s; s >>= 1) {
        if (threadIdx.x < s) sm[threadIdx.x] += sm[threadIdx.x + s];
        __syncthreads();
    }
    if (threadIdx.x == 0)
        outf[(size_t)B_ROWS * DIM + B_ROWS] = 1.25f * sm[0] / 16777216.0f;
}

extern "C" void kernel_launch(void* const* d_in, const int* in_sizes, int n_in,
                              void* d_out, int out_size, void* d_ws, size_t ws_size,
                              hipStream_t stream) {
    (void)in_sizes; (void)n_in; (void)out_size; (void)ws_size;
    const float* Zf = (const float*)d_in[0];   // [32768, 512] f32
    const float* Wf = (const float*)d_in[1];   // [8192, 512]  f32
    float* outf = (float*)d_out;               // f32: z_q | indices | loss

    // bf16 scratch inside d_out's z_q region (64 MB): Zh 32MB @0 | Wh 8MB @32MB.
    // k_exact overwrites it with the final z_q (k_argmin has completed by then).
    unsigned short* Zh = (unsigned short*)d_out;
    unsigned short* Wh = (unsigned short*)((char*)d_out + (32ull << 20));

    // ws (4.39 MB, proven): ww 32KB @0 | zz 128KB @32K | lossp 32KB @160K | part 4MB @192K
    // part layout: [row][super(4)][4 entries] float2 = 4MB.
    float*  ww    = (float*)d_ws;
    float*  zz    = (float*)((char*)d_ws + 32768);
    float*  lossp = (float*)((char*)d_ws + 163840);
    float2* partp = (float2*)((char*)d_ws + 196608);

    k_split<<<1024, 256, 0, stream>>>((const float4*)Zf, (ushort4*)Zh, B_ROWS * DIM / 4);
    k_split<<<512,  256, 0, stream>>>((const float4*)Wf, (ushort4*)Wh, KCODES * DIM / 4);
    k_pairsq<<<KCODES / 4, 256, 0, stream>>>(Wf, ww, KCODES);
    k_pairsq<<<B_ROWS / 4, 256, 0, stream>>>(Zf, zz, B_ROWS);
    k_argmin<<<(B_ROWS / ZROWS) * SUPERS, 256, 0, stream>>>(Zh, Wh, ww, partp);
    k_exact<<<B_ROWS / 4, 256, 0, stream>>>(Zf, Wf, partp, zz, ww, outf, lossp);
    k_loss<<<1, 256, 0, stream>>>(lossp, outf);
}

// Round 7
// 793.267 us; speedup vs baseline: 1.1465x; 1.0650x over previous
//
#include <hip/hip_runtime.h>
#include <stdint.h>

// VQ-VAE codebook argmin, f32 in / f32 out.
// R12 = R11 resubmit (round-6 bench died in infra: container failed during
// input push, kernel never ran; code re-audited, no defect found).
// R11: barrier-free K-loop. R10 post-mortem: one __syncthreads per K-step
// (512/block) costs ~1000cyc each (vmcnt(0)-drain of just-issued loads +
// 4-wave convoy) = the whole kernel. Fix: wave-PRIVATE W staging. Wave-tile
// 64 rows x 32 cols: each wave stages its own 32colx32k (2KB = 2 gl_lds16)
// into a private 2x2KB double buffer -> no inter-wave hand-off -> ZERO
// barriers in the K-loop. Sync is per-wave counted s_waitcnt vmcnt(2):
// stage(t) is always >=3 issues old at the wait (stage(t+1)=2 newer) ->
// provably landed; extra in-flight vmem (cb loads) only makes the wait
// stricter (vmcnt is issue-ordered). Tail drains vmcnt(0). Differs from
// R6's failure: no raw barriers, no inter-wave races (all wave-local),
// ds_reads are compiler-visible memory ops so the "memory" clobber orders
// them after the wait (rule-18 safe: hazard there was register-only MFMA).
// LDS: Z 64KB (stationary, R9-proven) + 4 waves x 4KB = 80KB -> exactly
// 2 blocks/CU; 2 waves/SIMD co-hide residual L2 latency. W cols disjoint
// per wave -> L2 traffic unchanged. Ranking retiled: per-lane-column top-2
// over (tl,fn) (32 cands, SAFER pruning than R10's 64), id=tl*2+fn, final
// reduce scans 128 keys/row (stride 130 = 2-way conflict, free per m136).
// k_exact numerics unchanged (16 exact-f32 candidates, R4-proven anchor).

#define B_ROWS 32768
#define DIM    512
#define KCODES 8192
#define SUPERS 4
#define TILES  16   // per super: 16 tiles * 128 = 2048 codes
#define ZROWS  64   // Z rows per block (stationary in LDS, full K)
#define NSTEP  256  // TILES * 16 K-steps (BK=32)

typedef short bhalf8_t __attribute__((ext_vector_type(8)));
typedef float f32x4_t  __attribute__((ext_vector_type(4)));

__device__ __forceinline__ float b2f(unsigned short u) {
    return __uint_as_float(((unsigned int)u) << 16);
}
__device__ __forceinline__ unsigned short f2b(float f) {  // RNE
    unsigned int x = __float_as_uint(f);
    return (unsigned short)((x + 0x7FFFu + ((x >> 16) & 1u)) >> 16);
}
__device__ __forceinline__ void gl_lds16(const void* g, void* l) {
    __builtin_amdgcn_global_load_lds(
        (const __attribute__((address_space(1))) unsigned int*)g,
        (__attribute__((address_space(3))) unsigned int*)l, 16, 0, 0);
}

// ---------- K0: f32 -> bf16 (hi only) ----------
__global__ __launch_bounds__(256) void k_split(const float4* __restrict__ src,
                                               ushort4* __restrict__ dst, int n4) {
    int i = blockIdx.x * 256 + threadIdx.x;
    int stride = gridDim.x * 256;
    for (; i < n4; i += stride) {
        float4 v = src[i];
        ushort4 h;
        h.x = f2b(v.x); h.y = f2b(v.y); h.z = f2b(v.z); h.w = f2b(v.w);
        dst[i] = h;
    }
}

// ---------- K1: numpy-pairwise-emulated row sum of squares (R4-proven) ----------
__global__ __launch_bounds__(256) void k_pairsq(const float* __restrict__ X,
                                                float* __restrict__ out, int nrows) {
    int wid = threadIdx.x >> 6, lane = threadIdx.x & 63;
    int r = blockIdx.x * 4 + wid;
    if (r >= nrows) return;
    int b = lane >> 3, j = lane & 7;
    float acc = 0.f;
    if (b < 4) {
        const float* x = X + (size_t)r * DIM + b * 128 + j;
        float v = x[0];
        acc = __fmul_rn(v, v);
        for (int i = 1; i < 16; i++) {
            float w = x[8 * i];
            acc = __fadd_rn(acc, __fmul_rn(w, w));
        }
    }
    float t = __fadd_rn(acc, __shfl_xor(acc, 1));
    t = __fadd_rn(t, __shfl_xor(t, 2));
    t = __fadd_rn(t, __shfl_xor(t, 4));
    float u = __fadd_rn(t, __shfl_xor(t, 8));
    u = __fadd_rn(u, __shfl_xor(u, 16));
    if (lane == 0) out[r] = u;
}

// ---------- K2: Z-stationary GEMM, wave-private W, barrier-free K-loop ----------
// LDS map (80KB): [0,64K) Z: 16 fragment-major 32-k slices of 64 rows
//                 [64K+w*4K, +2K) wave-w W buf0 | [+2K, +4K) buf1
// Fragment-major 32-k slice (HW-verified R6-R10): element (row, kseg) at byte
//   (row>>4)*1024 + kseg*256 + (row&15)*16
// Wave reads af[f] = zl + ks*4096 + f*1024 + lane*16 (contiguous 1024B,
// conflict-free), bf[f] = wbuf + f*1024 + lane*16. global_load_lds dest is
// LINEAR (wave base + lane*16); layout permutation applied to the per-lane
// GLOBAL source address (both-sides-or-neither rule).
__device__ __forceinline__ void compute_ks(const unsigned char* zl, int ks,
                                           const unsigned char* wbuf,
                                           int lane, f32x4_t acc[4][2]) {
    bhalf8_t af[4], bf[2];
#pragma unroll
    for (int f = 0; f < 4; f++)
        af[f] = *(const bhalf8_t*)(zl + ks * 4096 + f * 1024 + lane * 16);
#pragma unroll
    for (int f = 0; f < 2; f++)
        bf[f] = *(const bhalf8_t*)(wbuf + f * 1024 + lane * 16);
#pragma unroll
    for (int fm = 0; fm < 4; fm++)
#pragma unroll
        for (int fn = 0; fn < 2; fn++)
            acc[fm][fn] = __builtin_amdgcn_mfma_f32_16x16x32_bf16(af[fm], bf[fn], acc[fm][fn], 0, 0, 0);
}

__global__ __launch_bounds__(256) void k_argmin(const unsigned short* __restrict__ Zh,
                                                const unsigned short* __restrict__ Wh,
                                                const float* __restrict__ ww,
                                                float2* __restrict__ part) {
    __shared__ alignas(16) unsigned char smem[81920];
    const int tid = threadIdx.x;
    const int lane = tid & 63, w = tid >> 6;
    const int lane15 = lane & 15, q = lane >> 4;
    const int b = blockIdx.x;
    const int super = b & 3;          // XCD = b&7 -> one 2MB W-slice per XCD (L2-resident)
    const int rb = (b >> 2) * ZROWS;

    unsigned char* zl  = smem;                       // 64KB Z
    unsigned char* wpr = smem + 65536 + w * 4096;    // wave-private: buf0 @0, buf1 @+2048

    // ---- Z prologue: stage 64 rows x 512 k once (16 gl_lds16 per thread) ----
    // slot s = i*256 + tid; dest byte = s*16 (linear, lane-contiguous).
    // decode: ks=s>>8, g=(s>>6)&3, kseg=(s>>4)&3, m=s&15; row=g*16+m.
    {
        const int m = tid & 15;
        const int kseg8 = ((tid >> 4) & 3) << 3;
#pragma unroll
        for (int i = 0; i < 16; i++) {
            const int s = i * 256 + tid;
            const int ks = s >> 8;
            const int g = (s >> 6) & 3;
            gl_lds16(Zh + (size_t)(rb + g * 16 + m) * DIM + ks * 32 + kseg8,
                     zl + s * 16);
        }
    }

    // Wave-private W stage: this wave's 32 cols x 32 k (2KB) = 2 gl_lds16/lane.
    // Slice slot s in [0,128): col=(s>>6)*16+(s&15), kseg=(s>>4)&3.
    // lane covers s=lane (cols 0..15) and s=lane+64 (cols 16..31).
    const int colL = lane & 15;
    const int ksegL8 = (q & 3) << 3;
#define STAGE_W(ST, WB)                                                                   \
    do {                                                                                  \
        const int _nt = super * 2048 + ((ST) >> 4) * 128 + w * 32;                        \
        const int _kg = ((ST) & 15) * 32 + ksegL8;                                        \
        gl_lds16(Wh + (size_t)(_nt + colL) * DIM + _kg,      (WB) + lane * 16);           \
        gl_lds16(Wh + (size_t)(_nt + 16 + colL) * DIM + _kg, (WB) + 1024 + lane * 16);    \
    } while (0)

    uint32_t p1[4][4], p2[4][4];
#pragma unroll
    for (int i = 0; i < 4; i++)
#pragma unroll
        for (int jj = 0; jj < 4; jj++) { p1[i][jj] = 0xFFFFFFFFu; p2[i][jj] = 0xFFFFFFFFu; }

    STAGE_W(0, wpr);
    __syncthreads();   // Z + step-0 staged (compiler drains vmcnt before barrier)

    for (int tl = 0; tl < TILES; ++tl) {
        const int nt = super * 2048 + tl * 128;
        float cb[2];
        cb[0] = ww[nt + w * 32 + lane15] + 0.5f;
        cb[1] = ww[nt + w * 32 + 16 + lane15] + 0.5f;

        f32x4_t acc[4][2];
#pragma unroll
        for (int i = 0; i < 4; i++)
#pragma unroll
            for (int jj = 0; jj < 2; jj++) acc[i][jj] = (f32x4_t){0.f, 0.f, 0.f, 0.f};

        for (int k2 = 0; k2 < 16; k2 += 2) {
            const int st = tl * 16 + k2;
            // even: stage st+1 -> buf1, compute buf0. vmcnt(2): stage(st) is
            // >=3 issues old (stage(st+1)=2 newer) -> landed. In-order vmem
            // counting makes interleaved cb loads harmless (only stricter).
            STAGE_W(st + 1, wpr + 2048);
            asm volatile("s_waitcnt vmcnt(2)" ::: "memory");
            compute_ks(zl, k2, wpr, lane, acc);
            // odd: stage st+2 -> buf0 (if any), compute buf1.
            if (st + 2 < NSTEP) {
                STAGE_W(st + 2, wpr);
                asm volatile("s_waitcnt vmcnt(2)" ::: "memory");
            } else {
                asm volatile("s_waitcnt vmcnt(0)" ::: "memory");
            }
            compute_ks(zl, k2 + 1, wpr + 2048, lane, acc);
        }

        // epilogue: s' = (ww[n]+0.5) - 2*dot (positive => float bits monotonic);
        // pack: high-25 bits | id = tl*2+fn (<32, fits 7-bit field). Strict '<'
        // ascending (tl,fn) insert => smaller n wins ties within a lane-column.
#pragma unroll
        for (int fm = 0; fm < 4; fm++)
#pragma unroll
            for (int r = 0; r < 4; r++)
#pragma unroll
                for (int fn = 0; fn < 2; fn++) {
                    float sv = fmaf(-2.0f, acc[fm][fn][r], cb[fn]);
                    uint32_t pk = (__float_as_uint(sv) & 0xFFFFFF80u) | (uint32_t)(tl * 2 + fn);
                    if (pk < p1[fm][r]) { p2[fm][r] = p1[fm][r]; p1[fm][r] = pk; }
                    else if (pk < p2[fm][r]) { p2[fm][r] = pk; }
                }
    }
#undef STAGE_W

    // per-row top-4 of 128 packed keys via LDS (reuses Z region; stride 130
    // elements -> scan banks (2*row+e)%32: 2-way conflict = free, m136)
    __syncthreads();
    uint32_t* keys = (uint32_t*)smem;   // [64 rows][stride 130]: 128 keys + pad
#pragma unroll
    for (int fm = 0; fm < 4; fm++)
#pragma unroll
        for (int r = 0; r < 4; r++) {
            int row = fm * 16 + q * 4 + r;   // C/D row = (lane>>4)*4 + reg
            int sp = w * 16 + lane15;        // slot-position 0..63
            keys[row * 130 + sp * 2 + 0] = p1[fm][r];
            keys[row * 130 + sp * 2 + 1] = p2[fm][r];
        }
    __syncthreads();
    if (tid < ZROWS) {
        int row = tid;
        int rglob = rb + row;
        for (int s = 0; s < 4; s++) {
            uint32_t bk = 0xFFFFFFFFu; int be = 0;
            for (int e = 0; e < 128; e++) {
                uint32_t k = keys[row * 130 + e];
                if (k < bk) { bk = k; be = e; }
            }
            int sp = be >> 1;                 // w*16 + lane15
            int id = (int)(bk & 127u);        // tl*2 + fn
            int n = super * 2048 + (id >> 1) * 128 + (sp >> 4) * 32 + (id & 1) * 16 + (sp & 15);
            part[((size_t)rglob * SUPERS + super) * 4 + s] =
                make_float2(__uint_as_float(bk), __int_as_float(n));
            keys[row * 130 + be] = 0xFFFFFFFFu;  // consume
        }
    }
}

// ---------- K3: exact numpy-f32 re-rank of 16 candidates, outputs (R4-proven) ----------
__global__ __launch_bounds__(256) void k_exact(const float* __restrict__ Zf,
                                               const float* __restrict__ Wf,
                                               const float2* __restrict__ part,
                                               const float* __restrict__ zz,
                                               const float* __restrict__ ww,
                                               float* __restrict__ outf,
                                               float* __restrict__ lossp) {
    __shared__ float wsum[4];
    int wid = threadIdx.x >> 6, lane = threadIdx.x & 63;
    int r = blockIdx.x * 4 + wid;
    int c = lane >> 2, j = lane & 3;   // candidate 0..15, SSE lane 0..3

    // candidates: 4 supers x top-4
    float2 P = part[((size_t)r * SUPERS + (c >> 2)) * 4 + (c & 3)];
    int n = __float_as_int(P.y);
    n = min(max(n, 0), KCODES - 1);

    // numpy einsum baseline-SIMD: 4 stride-4 f32 accumulators (mul+add, no FMA)
    const float* zp = Zf + (size_t)r * DIM + j;
    const float* wp = Wf + (size_t)n * DIM + j;
    float acc = 0.f;
    for (int i = 0; i < 128; i++)
        acc = __fadd_rn(acc, __fmul_rn(zp[4 * i], wp[4 * i]));
    float t = __fadd_rn(acc, __shfl_xor(acc, 1));
    t = __fadd_rn(t, __shfl_xor(t, 2));
    float dot = __shfl(t, c * 4);

    float t1 = __fadd_rn(zz[r], ww[n]);
    float t2 = __fmul_rn(2.0f, dot);
    float d2 = __fadd_rn(t1, -t2);

    float bd = (j == 0) ? d2 : 3.4e38f;
    int   bn = (j == 0) ? n  : 0x7FFFFFFF;
#pragma unroll
    for (int off = 32; off; off >>= 1) {
        float od = __shfl_xor(bd, off);
        int   on = __shfl_xor(bn, off);
        if (od < bd || (od == bd && on < bn)) { bd = od; bn = on; }
    }
    int idx = bn;

    float4 wa = *(const float4*)(Wf + (size_t)idx * DIM + lane * 8);
    float4 wb = *(const float4*)(Wf + (size_t)idx * DIM + lane * 8 + 4);
    float4 za = *(const float4*)(Zf + (size_t)r   * DIM + lane * 8);
    float4 zb = *(const float4*)(Zf + (size_t)r   * DIM + lane * 8 + 4);
    *(float4*)(outf + (size_t)r * DIM + lane * 8)     = wa;
    *(float4*)(outf + (size_t)r * DIM + lane * 8 + 4) = wb;
    float d0 = za.x - wa.x, d1 = za.y - wa.y, dd2 = za.z - wa.z, d3 = za.w - wa.w;
    float d4 = zb.x - wb.x, d5 = zb.y - wb.y, d6 = zb.z - wb.z, d7 = zb.w - wb.w;
    float ls = d0*d0 + d1*d1 + dd2*dd2 + d3*d3 + d4*d4 + d5*d5 + d6*d6 + d7*d7;
#pragma unroll
    for (int off = 32; off; off >>= 1) ls += __shfl_xor(ls, off);
    if (lane == 0) {
        outf[(size_t)B_ROWS * DIM + r] = (float)idx;
        wsum[wid] = ls;
    }
    __syncthreads();
    if (threadIdx.x == 0) lossp[blockIdx.x] = wsum[0] + wsum[1] + wsum[2] + wsum[3];
}

// ---------- K4: loss reduction ----------
__global__ __launch_bounds__(256) void k_loss(const float* __restrict__ lossp,
                                              float* __restrict__ outf) {
    __shared__ float sm[256];
    float a = 0.f;
    for (int i = threadIdx.x; i < 8192; i += 256) a += lossp[i];
    sm[threadIdx.x] = a;
    __syncthreads();
    for (int s = 128; s; s >>= 1) {
        if (threadIdx.x < s) sm[threadIdx.x] += sm[threadIdx.x + s];
        __syncthreads();
    }
    if (threadIdx.x == 0)
        outf[(size_t)B_ROWS * DIM + B_ROWS] = 1.25f * sm[0] / 16777216.0f;
}

extern "C" void kernel_launch(void* const* d_in, const int* in_sizes, int n_in,
                              void* d_out, int out_size, void* d_ws, size_t ws_size,
                              hipStream_t stream) {
    (void)in_sizes; (void)n_in; (void)out_size; (void)ws_size;
    const float* Zf = (const float*)d_in[0];   // [32768, 512] f32
    const float* Wf = (const float*)d_in[1];   // [8192, 512]  f32
    float* outf = (float*)d_out;               // f32: z_q | indices | loss

    // bf16 scratch inside d_out's z_q region (64 MB): Zh 32MB @0 | Wh 8MB @32MB.
    // k_exact overwrites it with the final z_q (k_argmin has completed by then).
    unsigned short* Zh = (unsigned short*)d_out;
    unsigned short* Wh = (unsigned short*)((char*)d_out + (32ull << 20));

    // ws (4.39 MB, proven): ww 32KB @0 | zz 128KB @32K | lossp 32KB @160K | part 4MB @192K
    // part layout: [row][super(4)][4 entries] float2 = 4MB.
    float*  ww    = (float*)d_ws;
    float*  zz    = (float*)((char*)d_ws + 32768);
    float*  lossp = (float*)((char*)d_ws + 163840);
    float2* partp = (float2*)((char*)d_ws + 196608);

    k_split<<<1024, 256, 0, stream>>>((const float4*)Zf, (ushort4*)Zh, B_ROWS * DIM / 4);
    k_split<<<512,  256, 0, stream>>>((const float4*)Wf, (ushort4*)Wh, KCODES * DIM / 4);
    k_pairsq<<<KCODES / 4, 256, 0, stream>>>(Wf, ww, KCODES);
    k_pairsq<<<B_ROWS / 4, 256, 0, stream>>>(Zf, zz, B_ROWS);
    k_argmin<<<(B_ROWS / ZROWS) * SUPERS, 256, 0, stream>>>(Zh, Wh, ww, partp);
    k_exact<<<B_ROWS / 4, 256, 0, stream>>>(Zf, Wf, partp, zz, ww, outf, lossp);
    k_loss<<<1, 256, 0, stream>>>(lossp, outf);
}